// Round 7
// baseline (152.008 us; speedup 1.0000x reference)
//
#include <hip/hip_runtime.h>

// BLAMem: truncated tensor-algebra (depth 4, C=8) log-signature memory.
// 5 stream-ordered dispatches (kernel boundaries are the only cross-block sync —
// round-6 lesson: flag-based cross-XCD sync raced under graph replay).
// Identities:
//  (1) BCH-prefix-scan of chunk log-sigs == ta_log of ta_mul-prefix-scan of chunk sigs.
//  (2) Chen fold over a 16-step chunk in closed parallel form; producer threads
//      accumulate their own L4 row (no G-table).
//  (3) ta_mul prefix over group totals is lower-triangular -> cascaded prefix sums.

#define MEM   4680   // 8 + 64 + 512 + 4096
#define L2OFF 8
#define L3OFF 72
#define L4OFF 584
#define NG    32     // groups per batch
#define TLEN  2048
#define ZN    (8 * MEM + 8 * 256)   // pooled + hbuf zero region

// Load the 64 per-step increments for group (b,g) into sInc[512].
__device__ __forceinline__ void load_inc(const float* __restrict__ x, int b, int g,
                                         float* sInc, int tid) {
    for (int e = tid; e < 512; e += 256) {
        int s = e >> 3, c = e & 7;
        int t = g * 64 + s;
        float v;
        if (c < 7) {
            float cur  = x[(b * TLEN + t) * 7 + c];
            float prev = (t > 0) ? x[(b * TLEN + t - 1) * 7 + c] : 0.f;
            v = cur - prev;
        } else v = (t > 0) ? (1.f / 2047.f) : 0.f;
        sInc[e] = v;
    }
}

// Fold the chunk-local signature (16 steps, closed form) into running product sA.
// Thread owns L4 rows ijk=tid and ijk=tid+256 (8 l-values each), L3 pos tid & tid+256.
// U: scratch >= 584 floats (loc3 512 | loc2 64 | loc1 8).
__device__ __forceinline__ void chunk_step(const float* dch, float* sA, float* U, int tid) {
    float* loc3 = U;
    float* loc2 = U + 512;
    float* loc1 = U + 576;
    const int i1 = tid >> 6, j1 = (tid >> 3) & 7, k1 = tid & 7;
    const int pos2 = tid + 256, i2 = pos2 >> 6;
    float p1a = 0.f, l2a = 0.f, l3a = 0.f, p1b = 0.f, l2b = 0.f, l3b = 0.f;
    float Sa[8], Sb[8];
#pragma unroll
    for (int l = 0; l < 8; l++) { Sa[l] = 0.f; Sb[l] = 0.f; }
#pragma unroll
    for (int t = 0; t < 16; t++) {
        const float* dr = dch + t * 8;
        float di1 = dr[i1], di2 = dr[i2], dj = dr[j1], dk = dr[k1];
        float ga = l3a + dk * (l2a * 0.5f + dj * (p1a * (1.f/6.f) + di1 * (1.f/24.f)));
        float gb = l3b + dk * (l2b * 0.5f + dj * (p1b * (1.f/6.f) + di2 * (1.f/24.f)));
#pragma unroll
        for (int l = 0; l < 8; l++) { float dv = dr[l]; Sa[l] += ga * dv; Sb[l] += gb * dv; }
        l3a += dk * (l2a + dj * (p1a * 0.5f + di1 * (1.f/6.f)));
        l3b += dk * (l2b + dj * (p1b * 0.5f + di2 * (1.f/6.f)));
        l2a += (p1a + di1 * 0.5f) * dj;
        l2b += (p1b + di2 * 0.5f) * dj;
        p1a += di1; p1b += di2;
    }
    loc3[tid] = l3a; loc3[pos2] = l3b;
    if (k1 == 0) { loc2[tid >> 3] = l2a; loc2[(tid >> 3) + 32] = l2b; }
    if ((tid & 63) == 0) { loc1[i1] = p1a; loc1[i2] = p1b; }
    __syncthreads();
    float n4a[8], n4b[8];
    {
        float a1 = sA[i1], a2 = sA[L2OFF + (tid >> 3)], a3 = sA[L3OFF + tid];
        float c1_ = sA[i2], c2_ = sA[L2OFF + (tid >> 3) + 32], c3_ = sA[L3OFF + pos2];
        const float* l3p = &loc3[(tid & 63) * 8];
        const float* l2p = &loc2[k1 * 8];
#pragma unroll
        for (int l = 0; l < 8; l++) {
            float v3 = l3p[l], v2 = l2p[l], v1 = loc1[l];
            n4a[l] = sA[L4OFF + tid * 8 + l]  + Sa[l] + a1 * v3 + a2 * v2 + a3 * v1;
            n4b[l] = sA[L4OFF + pos2 * 8 + l] + Sb[l] + c1_ * v3 + c2_ * v2 + c3_ * v1;
        }
    }
    float n3a = sA[L3OFF + tid]  + l3a + sA[i1] * loc2[tid & 63] + sA[L2OFF + (tid >> 3)] * loc1[k1];
    float n3b = sA[L3OFF + pos2] + l3b + sA[i2] * loc2[tid & 63] + sA[L2OFF + (tid >> 3) + 32] * loc1[k1];
    float n2v = 0.f, n1v = 0.f;
    if (tid < 64) n2v = sA[L2OFF + tid] + loc2[tid] + sA[tid >> 3] * loc1[tid & 7];
    if (tid < 8)  n1v = sA[tid] + loc1[tid];
    __syncthreads();
#pragma unroll
    for (int l = 0; l < 8; l++) { sA[L4OFF + tid * 8 + l] = n4a[l]; sA[L4OFF + pos2 * 8 + l] = n4b[l]; }
    sA[L3OFF + tid] = n3a; sA[L3OFF + pos2] = n3b;
    if (tid < 64) sA[L2OFF + tid] = n2v;
    if (tid < 8)  sA[tid] = n1v;
    __syncthreads();
}

// ------------------------------------------------ kernel 1: group totals (+ fused zero)
__global__ __launch_bounds__(256) void sig_totals_kernel(const float* __restrict__ x,
                                                         float* __restrict__ T,
                                                         float* __restrict__ zbuf) {
    int blk = blockIdx.x;
    int b = blk >> 5, g = blk & 31;
    int tid = threadIdx.x;

    for (int i = blk * 256 + tid; i < ZN; i += 256 * 256) zbuf[i] = 0.f;

    __shared__ __attribute__((aligned(16))) float sInc[512];
    __shared__ __attribute__((aligned(16))) float sA[MEM];
    __shared__ __attribute__((aligned(16))) float U[584];

    load_inc(x, b, g, sInc, tid);
    for (int m = tid; m < MEM; m += 256) sA[m] = 0.f;
    __syncthreads();
    for (int c = 0; c < 4; c++) chunk_step(&sInc[c * 128], sA, U, tid);
    const float4* s4 = (const float4*)sA;
    float4* t4 = (float4*)(T + (size_t)blk * MEM);
    for (int m = tid; m < MEM / 4; m += 256) t4[m] = s4[m];
}

// ------------------------------------------------ kernel 2: cascade scan over T -> P
// grid = 8 b x 16 slices. Exclusive ta_mul prefixes of the 32 group totals.
__global__ __launch_bounds__(256) void scan_fused_kernel(const float* __restrict__ T,
                                                         float* __restrict__ P) {
    int bx = blockIdx.x;
    int b = bx >> 4, s = bx & 15;
    int tid = threadIdx.x;

    __shared__ float st1[NG][8];
    __shared__ float st2[NG][64];
    __shared__ float st3[NG][32];
    __shared__ float sp1[NG][8];
    __shared__ float sp2[NG][64];
    __shared__ float sp3[NG][32];

    int bBase = b * NG;
    {
        int g = tid >> 3, i = tid & 7;
        st1[g][i] = T[(size_t)(bBase + g) * MEM + i];
    }
    for (int m = tid; m < NG * 64; m += 256) {
        int g = m >> 6, e = m & 63;
        st2[g][e] = T[(size_t)(bBase + g) * MEM + L2OFF + e];
    }
    for (int m = tid; m < NG * 32; m += 256) {
        int g = m >> 5, e = m & 31;
        st3[g][e] = T[(size_t)(bBase + g) * MEM + L3OFF + s * 32 + e];
    }
    __syncthreads();

    if (tid < 64) {
        int i = tid >> 3, k = tid & 7;
        float p1acc = 0.f, p2acc = 0.f;
        for (int g = 0; g < NG; g++) {
            sp2[g][tid] = p2acc;
            if (k == 0) sp1[g][i] = p1acc;
            if (s == 0) {
                size_t prow = (size_t)(bBase + g) * MEM;
                P[prow + L2OFF + tid] = p2acc;
                if (k == 0) P[prow + i] = p1acc;
            }
            p2acc += st2[g][tid] + p1acc * st1[g][k];
            p1acc += st1[g][i];
        }
    }
    __syncthreads();
    if (tid < 32) {
        int ijk = s * 32 + tid;
        int i = ijk >> 6, jk = ijk & 63, ij = ijk >> 3, k = ijk & 7;
        float acc3 = 0.f;
        for (int g = 0; g < NG; g++) {
            sp3[g][tid] = acc3;
            P[(size_t)(bBase + g) * MEM + L3OFF + ijk] = acc3;
            acc3 += st3[g][tid] + sp1[g][i] * st2[g][jk] + sp2[g][ij] * st1[g][k];
        }
    }
    __syncthreads();
    {
        int m = s * 256 + tid;
        int i = m >> 9, jkl = m & 511, ij = m >> 6, kl = m & 63, l = m & 7;
        int p3loc = tid >> 3;
        float acc4 = 0.f;
#pragma unroll 4
        for (int g = 0; g < NG; g++) {
            size_t row = (size_t)(bBase + g) * MEM;
            P[row + L4OFF + m] = acc4;
            acc4 += T[row + L4OFF + m]
                  + sp1[g][i] * T[row + L3OFF + jkl]
                  + sp2[g][ij] * st2[g][kl]
                  + sp3[g][p3loc] * st1[g][l];
        }
    }
}

// ------------------------------------------------ kernel 3: recompute chunks + apply + log + pool
__global__ __launch_bounds__(256) void apply_log_pool_kernel(const float* __restrict__ x,
                                                             const float* __restrict__ P,
                                                             float* __restrict__ pooled) {
    int blk = blockIdx.x;
    int b = blk >> 5, g = blk & 31;
    int tid = threadIdx.x;

    __shared__ __attribute__((aligned(16))) float sInc[512];
    __shared__ __attribute__((aligned(16))) float sA[MEM];
    __shared__ __attribute__((aligned(16))) float sP[MEM];
    __shared__ __attribute__((aligned(16))) float U[1680];

    load_inc(x, b, g, sInc, tid);
    {
        const float4* p4 = (const float4*)(P + (size_t)blk * MEM);
        float4* sp4 = (float4*)sP;
        for (int m = tid; m < MEM / 4; m += 256) sp4[m] = p4[m];
    }
    for (int m = tid; m < MEM; m += 256) sA[m] = 0.f;
    __syncthreads();

    const int i1 = tid >> 6, j1 = (tid >> 3) & 7, k1 = tid & 7;
    const int pos2 = tid + 256, i2 = pos2 >> 6;
    float pool4a[8], pool4b[8];
#pragma unroll
    for (int l = 0; l < 8; l++) { pool4a[l] = 0.f; pool4b[l] = 0.f; }
    float pool3a = 0.f, pool3b = 0.f, pool2 = 0.f, pool1 = 0.f;
    float* sR = U + 584;      // R levels 1..3 (584)
    float* sQ23 = U + 1168;   // (R^2) level 3 (512)

    for (int c = 0; c < 4; c++) {
        chunk_step(&sInc[c * 128], sA, U, tid);   // sA = cumulative chunk sig
        float R4a[8], R4b[8];
        {
            float a1 = sP[i1], a2 = sP[L2OFF + (tid >> 3)], a3 = sP[L3OFF + tid];
            float c1_ = sP[i2], c2_ = sP[L2OFF + (tid >> 3) + 32], c3_ = sP[L3OFF + pos2];
            const float* q3p = &sA[L3OFF + (tid & 63) * 8];
            const float* q2p = &sA[L2OFF + k1 * 8];
#pragma unroll
            for (int l = 0; l < 8; l++) {
                float v3 = q3p[l], v2 = q2p[l], v1 = sA[l];
                R4a[l] = sP[L4OFF + tid * 8 + l]  + sA[L4OFF + tid * 8 + l]  + a1 * v3 + a2 * v2 + a3 * v1;
                R4b[l] = sP[L4OFF + pos2 * 8 + l] + sA[L4OFF + pos2 * 8 + l] + c1_ * v3 + c2_ * v2 + c3_ * v1;
            }
        }
        float R3a = sP[L3OFF + tid]  + sA[L3OFF + tid]  + sP[i1] * sA[L2OFF + (tid & 63)] + sP[L2OFF + (tid >> 3)] * sA[k1];
        float R3b = sP[L3OFF + pos2] + sA[L3OFF + pos2] + sP[i2] * sA[L2OFF + (tid & 63)] + sP[L2OFF + (tid >> 3) + 32] * sA[k1];
        float R2v = 0.f, R1v = 0.f;
        if (tid < 64) R2v = sP[L2OFF + tid] + sA[L2OFF + tid] + sP[tid >> 3] * sA[tid & 7];
        if (tid < 8)  R1v = sP[tid] + sA[tid];
        sR[72 + tid] = R3a; sR[72 + pos2] = R3b;
        if (tid < 64) sR[8 + tid] = R2v;
        if (tid < 8)  sR[tid] = R1v;
        __syncthreads();
        sQ23[tid]  = sR[tid >> 6] * sR[8 + (tid & 63)] + sR[8 + (tid >> 3)] * sR[tid & 7];
        sQ23[pos2] = sR[pos2 >> 6] * sR[8 + (tid & 63)] + sR[8 + (tid >> 3) + 32] * sR[tid & 7];
        __syncthreads();
        {
            float s1ia = sR[i1], s1ib = sR[i2], s1j = sR[j1], s1k = sR[k1];
            float s2ija = sR[8 + (tid >> 3)], s2ijb = sR[8 + (tid >> 3) + 32];
            const float* r3p = &sR[72 + (tid & 63) * 8];
            const float* r2p = &sR[8 + k1 * 8];
            const float* q23p = &sQ23[(tid & 63) * 8];
#pragma unroll
            for (int l = 0; l < 8; l++) {
                float s1l = sR[l];
                float p22 = s1k * s1l;
                float p24a = s1ia * r3p[l] + s2ija * r2p[l] + R3a * s1l;
                float p24b = s1ib * r3p[l] + s2ijb * r2p[l] + R3b * s1l;
                float p34a = s1ia * q23p[l] + s2ija * p22;
                float p34b = s1ib * q23p[l] + s2ijb * p22;
                float p44a = s1ia * s1j * p22;
                float p44b = s1ib * s1j * p22;
                pool4a[l] += R4a[l] - 0.5f * p24a + (1.f/3.f) * p34a - 0.25f * p44a;
                pool4b[l] += R4b[l] - 0.5f * p24b + (1.f/3.f) * p34b - 0.25f * p44b;
            }
            pool3a += R3a - 0.5f * sQ23[tid]  + (1.f/3.f) * s1ia * s1j * s1k;
            pool3b += R3b - 0.5f * sQ23[pos2] + (1.f/3.f) * s1ib * s1j * s1k;
            if (tid < 64) pool2 += R2v - 0.5f * sR[tid >> 3] * sR[tid & 7];
            if (tid < 8)  pool1 += R1v;
        }
        __syncthreads();
    }
    {
        const float sc = 1.f / 128.f;
        float* pb = pooled + (size_t)b * MEM;
#pragma unroll
        for (int l = 0; l < 8; l++) {
            atomicAdd(&pb[L4OFF + tid * 8 + l],  pool4a[l] * sc);
            atomicAdd(&pb[L4OFF + pos2 * 8 + l], pool4b[l] * sc);
        }
        atomicAdd(&pb[L3OFF + tid],  pool3a * sc);
        atomicAdd(&pb[L3OFF + pos2], pool3b * sc);
        if (tid < 64) atomicAdd(&pb[L2OFF + tid], pool2 * sc);
        if (tid < 8)  atomicAdd(&pb[tid], pool1 * sc);
    }
}

// ------------------------------------------------ kernel 4: gemv (W1 read once)
__global__ __launch_bounds__(256) void gemv1_kernel(const float* __restrict__ pooled,
                                                    const float* __restrict__ W1,
                                                    float* __restrict__ hbuf) {
    int kc = blockIdx.x;
    int tid = threadIdx.x;
    int k0 = kc * 32;
    __shared__ float sp[8][32];
    {
        int b = tid >> 5, kk = tid & 31;
        sp[b][kk] = (k0 + kk < MEM) ? pooled[b * MEM + k0 + kk] : 0.f;
    }
    __syncthreads();
    float acc[8];
#pragma unroll
    for (int b = 0; b < 8; b++) acc[b] = 0.f;
    int kend = (k0 + 32 < MEM) ? (k0 + 32) : MEM;
    for (int k = k0; k < kend; k++) {
        float wv = W1[(size_t)k * 256 + tid];
#pragma unroll
        for (int b = 0; b < 8; b++) acc[b] += sp[b][k - k0] * wv;
    }
#pragma unroll
    for (int b = 0; b < 8; b++) atomicAdd(&hbuf[b * 256 + tid], acc[b]);
}

// ------------------------------------------------ kernel 5: final MLP
__global__ __launch_bounds__(256) void final_kernel(const float* __restrict__ hbuf,
                                                    const float* __restrict__ b1,
                                                    const float* __restrict__ W2,
                                                    const float* __restrict__ b2,
                                                    float* __restrict__ outp) {
    int b = blockIdx.x;
    int tid = threadIdx.x;
    float v = hbuf[b * 256 + tid] + b1[tid];
    v = fmaxf(v, 0.f) * W2[tid];
    __shared__ float sRed[256];
    sRed[tid] = v;
    __syncthreads();
    for (int s = 128; s > 0; s >>= 1) {
        if (tid < s) sRed[tid] += sRed[tid + s];
        __syncthreads();
    }
    if (tid == 0) outp[b] = sRed[0] + b2[0];
}

// ------------------------------------------------ launch
extern "C" void kernel_launch(void* const* d_in, const int* in_sizes, int n_in,
                              void* d_out, int out_size, void* d_ws, size_t ws_size,
                              hipStream_t stream) {
    const float* x  = (const float*)d_in[0];
    const float* W1 = (const float*)d_in[1];
    const float* b1 = (const float*)d_in[2];
    const float* W2 = (const float*)d_in[3];
    const float* b2 = (const float*)d_in[4];
    float* out = (float*)d_out;

    float* ws = (float*)d_ws;
    float* T      = ws;                          // 256*MEM (group totals)
    float* P      = T + (size_t)256 * MEM;       // 256*MEM (exclusive prefixes)
    float* pooled = P + (size_t)256 * MEM;       // 8*MEM
    float* hbuf   = pooled + 8 * MEM;            // 8*256 (pooled+hbuf zeroed in kernel 1)

    sig_totals_kernel<<<256, 256, 0, stream>>>(x, T, pooled);
    scan_fused_kernel<<<128, 256, 0, stream>>>(T, P);
    apply_log_pool_kernel<<<256, 256, 0, stream>>>(x, P, pooled);
    gemv1_kernel<<<147, 256, 0, stream>>>(pooled, W1, hbuf);
    final_kernel<<<8, 256, 0, stream>>>(hbuf, b1, W2, b2, out);
}

// Round 8
// 126.781 us; speedup vs baseline: 1.1990x; 1.1990x over previous
//
#include <hip/hip_runtime.h>

// BLAMem: truncated tensor-algebra (depth 4, C=8) log-signature memory.
// 5 stream-ordered dispatches (kernel boundaries are the only cross-block sync).
// Round-7 lessons baked in: (a) NO device-scope atomics for reductions (cross-XCD
// atomic RMW thrashes ~28 B/op of HBM writeback — 33 MB seen); (b) all row-addressed
// LDS regions padded to stride 9 (stride-8 gave 16-way bank conflicts, 835K counted).
// Identities:
//  (1) BCH-prefix-scan of chunk log-sigs == ta_log of ta_mul-prefix-scan of chunk sigs.
//  (2) Chen fold over a 16-step chunk in closed parallel form (per-thread recurrences).
//  (3) ta_mul prefix over group totals is lower-triangular -> cascaded prefix sums.

#define MEM   4680   // 8 + 64 + 512 + 4096 (unpadded global layout)
#define NG    32     // groups per batch
#define TLEN  2048

// Padded LDS signature layout: L1 [0,8), L2 [8,72), L3 rows (i*8+j)*9+k at 72 (576),
// L4 rows ijk*9+l at 648 (4608). Total 5256 floats.
#define P3OFF 72
#define P4OFF 648
#define SIGSZ 5256

// Load the 64 per-step increments for group (b,g) into sInc[512].
__device__ __forceinline__ void load_inc(const float* __restrict__ x, int b, int g,
                                         float* sInc, int tid) {
    for (int e = tid; e < 512; e += 256) {
        int s = e >> 3, c = e & 7;
        int t = g * 64 + s;
        float v;
        if (c < 7) {
            float cur  = x[(b * TLEN + t) * 7 + c];
            float prev = (t > 0) ? x[(b * TLEN + t - 1) * 7 + c] : 0.f;
            v = cur - prev;
        } else v = (t > 0) ? (1.f / 2047.f) : 0.f;
        sInc[e] = v;
    }
}

// Fold chunk-local signature (16 steps, closed form) into running padded product sA.
// U scratch: loc3 padded 576 | loc2 64 | loc1 8 = 648 floats.
__device__ __forceinline__ void chunk_step(const float* dch, float* sA, float* U, int tid) {
    float* loc3 = U;
    float* loc2 = U + 576;
    float* loc1 = U + 640;
    const int i1 = tid >> 6, j1 = (tid >> 3) & 7, k1 = tid & 7;
    const int row1 = tid >> 3, row2 = row1 + 32;   // (i*8+j) for pos1/pos2
    const int jk = tid & 63;
    const int pos2 = tid + 256, i2 = pos2 >> 6;
    float p1a = 0.f, l2a = 0.f, l3a = 0.f, p1b = 0.f, l2b = 0.f, l3b = 0.f;
    float Sa[8], Sb[8];
#pragma unroll
    for (int l = 0; l < 8; l++) { Sa[l] = 0.f; Sb[l] = 0.f; }
#pragma unroll
    for (int t = 0; t < 16; t++) {
        const float* dr = dch + t * 8;
        float di1 = dr[i1], di2 = dr[i2], dj = dr[j1], dk = dr[k1];
        float ga = l3a + dk * (l2a * 0.5f + dj * (p1a * (1.f/6.f) + di1 * (1.f/24.f)));
        float gb = l3b + dk * (l2b * 0.5f + dj * (p1b * (1.f/6.f) + di2 * (1.f/24.f)));
#pragma unroll
        for (int l = 0; l < 8; l++) { float dv = dr[l]; Sa[l] += ga * dv; Sb[l] += gb * dv; }
        l3a += dk * (l2a + dj * (p1a * 0.5f + di1 * (1.f/6.f)));
        l3b += dk * (l2b + dj * (p1b * 0.5f + di2 * (1.f/6.f)));
        l2a += (p1a + di1 * 0.5f) * dj;
        l2b += (p1b + di2 * 0.5f) * dj;
        p1a += di1; p1b += di2;
    }
    loc3[row1 * 9 + k1] = l3a;
    loc3[row2 * 9 + k1] = l3b;
    if (k1 == 0) { loc2[row1] = l2a; loc2[row2] = l2b; }
    if (jk == 0) { loc1[i1] = p1a; loc1[i2] = p1b; }
    __syncthreads();
    float a1 = sA[i1], a2 = sA[8 + row1], a3 = sA[P3OFF + row1 * 9 + k1];
    float c1_ = sA[i2], c2_ = sA[8 + row2], c3_ = sA[P3OFF + row2 * 9 + k1];
    const float* l3p = &loc3[jk * 9];
    const float* l2p = &loc2[k1 * 8];
    float n4a[8], n4b[8];
#pragma unroll
    for (int l = 0; l < 8; l++) {
        float v3 = l3p[l], v2 = l2p[l], v1 = loc1[l];
        n4a[l] = sA[P4OFF + tid * 9 + l]  + Sa[l] + a1 * v3 + a2 * v2 + a3 * v1;
        n4b[l] = sA[P4OFF + pos2 * 9 + l] + Sb[l] + c1_ * v3 + c2_ * v2 + c3_ * v1;
    }
    float n3a = a3 + l3a + a1 * loc2[jk] + a2 * loc1[k1];
    float n3b = c3_ + l3b + c1_ * loc2[jk] + c2_ * loc1[k1];
    float n2v = 0.f, n1v = 0.f;
    if (tid < 64) n2v = sA[8 + tid] + loc2[tid] + sA[tid >> 3] * loc1[tid & 7];
    if (tid < 8)  n1v = sA[tid] + loc1[tid];
    __syncthreads();
#pragma unroll
    for (int l = 0; l < 8; l++) { sA[P4OFF + tid * 9 + l] = n4a[l]; sA[P4OFF + pos2 * 9 + l] = n4b[l]; }
    sA[P3OFF + row1 * 9 + k1] = n3a;
    sA[P3OFF + row2 * 9 + k1] = n3b;
    if (tid < 64) sA[8 + tid] = n2v;
    if (tid < 8)  sA[tid] = n1v;
    __syncthreads();
}

// ------------------------------------------------ kernel 1: group totals -> T (unpadded)
__global__ __launch_bounds__(256) void sig_totals_kernel(const float* __restrict__ x,
                                                         float* __restrict__ T) {
    int blk = blockIdx.x;
    int b = blk >> 5, g = blk & 31;
    int tid = threadIdx.x;

    __shared__ __attribute__((aligned(16))) float sInc[512];
    __shared__ __attribute__((aligned(16))) float sA[SIGSZ];
    __shared__ __attribute__((aligned(16))) float U[648];

    load_inc(x, b, g, sInc, tid);
    for (int m = tid; m < SIGSZ; m += 256) sA[m] = 0.f;
    __syncthreads();
    for (int c = 0; c < 4; c++) chunk_step(&sInc[c * 128], sA, U, tid);

    size_t base = (size_t)blk * MEM;
    for (int m = tid; m < MEM; m += 256) {
        float v;
        if (m < 72) v = sA[m];
        else if (m < 584) { int e = m - 72;  v = sA[P3OFF + (e >> 3) * 9 + (e & 7)]; }
        else              { int e = m - 584; v = sA[P4OFF + (e >> 3) * 9 + (e & 7)]; }
        T[base + m] = v;
    }
}

// ------------------------------------------------ kernel 2: cascade scan T -> P (unpadded)
__global__ __launch_bounds__(256) void scan_fused_kernel(const float* __restrict__ T,
                                                         float* __restrict__ P) {
    int bx = blockIdx.x;
    int b = bx >> 4, s = bx & 15;
    int tid = threadIdx.x;

    __shared__ float st1[NG][8];
    __shared__ float st2[NG][64];
    __shared__ float st3[NG][32];
    __shared__ float sp1[NG][8];
    __shared__ float sp2[NG][64];
    __shared__ float sp3[NG][32];

    int bBase = b * NG;
    {
        int g = tid >> 3, i = tid & 7;
        st1[g][i] = T[(size_t)(bBase + g) * MEM + i];
    }
    for (int m = tid; m < NG * 64; m += 256) {
        int g = m >> 6, e = m & 63;
        st2[g][e] = T[(size_t)(bBase + g) * MEM + 8 + e];
    }
    for (int m = tid; m < NG * 32; m += 256) {
        int g = m >> 5, e = m & 31;
        st3[g][e] = T[(size_t)(bBase + g) * MEM + 72 + s * 32 + e];
    }
    __syncthreads();

    if (tid < 64) {
        int i = tid >> 3, k = tid & 7;
        float p1acc = 0.f, p2acc = 0.f;
        for (int g = 0; g < NG; g++) {
            sp2[g][tid] = p2acc;
            if (k == 0) sp1[g][i] = p1acc;
            if (s == 0) {
                size_t prow = (size_t)(bBase + g) * MEM;
                P[prow + 8 + tid] = p2acc;
                if (k == 0) P[prow + i] = p1acc;
            }
            p2acc += st2[g][tid] + p1acc * st1[g][k];
            p1acc += st1[g][i];
        }
    }
    __syncthreads();
    if (tid < 32) {
        int ijk = s * 32 + tid;
        int i = ijk >> 6, jk = ijk & 63, ij = ijk >> 3, k = ijk & 7;
        float acc3 = 0.f;
        for (int g = 0; g < NG; g++) {
            sp3[g][tid] = acc3;
            P[(size_t)(bBase + g) * MEM + 72 + ijk] = acc3;
            acc3 += st3[g][tid] + sp1[g][i] * st2[g][jk] + sp2[g][ij] * st1[g][k];
        }
    }
    __syncthreads();
    {
        int m = s * 256 + tid;
        int i = m >> 9, jkl = m & 511, ij = m >> 6, kl = m & 63, l = m & 7;
        int p3loc = tid >> 3;
        float acc4 = 0.f;
#pragma unroll 4
        for (int g = 0; g < NG; g++) {
            size_t row = (size_t)(bBase + g) * MEM;
            P[row + 584 + m] = acc4;
            acc4 += T[row + 584 + m]
                  + sp1[g][i] * T[row + 72 + jkl]
                  + sp2[g][ij] * st2[g][kl]
                  + sp3[g][p3loc] * st1[g][l];
        }
    }
}

// ------------------------------------------------ kernel 3: recompute chunks + apply + log,
// write per-block pooled partial (NO atomics).
__global__ __launch_bounds__(256) void apply_log_pool_kernel(const float* __restrict__ x,
                                                             const float* __restrict__ P,
                                                             float* __restrict__ partial) {
    int blk = blockIdx.x;
    int b = blk >> 5, g = blk & 31;
    int tid = threadIdx.x;

    __shared__ __attribute__((aligned(16))) float sInc[512];
    __shared__ __attribute__((aligned(16))) float sA[SIGSZ];
    __shared__ __attribute__((aligned(16))) float sP[SIGSZ];
    __shared__ __attribute__((aligned(16))) float U[648];
    __shared__ __attribute__((aligned(16))) float sR[648];    // L1 8 | L2 64 | L3 pad 576
    __shared__ __attribute__((aligned(16))) float sQ23[576];  // padded rows of 9

    load_inc(x, b, g, sInc, tid);
    {
        size_t base = (size_t)blk * MEM;
        if (tid < 72) sP[tid] = P[base + tid];
        for (int e = tid; e < 512; e += 256)
            sP[P3OFF + (e >> 3) * 9 + (e & 7)] = P[base + 72 + e];
        for (int e = tid; e < 4096; e += 256)
            sP[P4OFF + (e >> 3) * 9 + (e & 7)] = P[base + 584 + e];
    }
    for (int m = tid; m < SIGSZ; m += 256) sA[m] = 0.f;
    __syncthreads();

    const int i1 = tid >> 6, j1 = (tid >> 3) & 7, k1 = tid & 7;
    const int row1 = tid >> 3, row2 = row1 + 32;
    const int jk = tid & 63;
    const int pos2 = tid + 256, i2 = pos2 >> 6;

    float pool4a[8], pool4b[8];
#pragma unroll
    for (int l = 0; l < 8; l++) { pool4a[l] = 0.f; pool4b[l] = 0.f; }
    float pool3a = 0.f, pool3b = 0.f, pool2 = 0.f, pool1 = 0.f;

    for (int c = 0; c < 4; c++) {
        chunk_step(&sInc[c * 128], sA, U, tid);   // sA = cumulative chunk sig (padded)

        float a1 = sP[i1], a2 = sP[8 + row1], a3 = sP[P3OFF + row1 * 9 + k1];
        float c1_ = sP[i2], c2_ = sP[8 + row2], c3_ = sP[P3OFF + row2 * 9 + k1];
        const float* q3p = &sA[P3OFF + jk * 9];
        const float* q2p = &sA[8 + k1 * 8];
        float R4a[8], R4b[8];
#pragma unroll
        for (int l = 0; l < 8; l++) {
            float v3 = q3p[l], v2 = q2p[l], v1 = sA[l];
            R4a[l] = sP[P4OFF + tid * 9 + l]  + sA[P4OFF + tid * 9 + l]  + a1 * v3 + a2 * v2 + a3 * v1;
            R4b[l] = sP[P4OFF + pos2 * 9 + l] + sA[P4OFF + pos2 * 9 + l] + c1_ * v3 + c2_ * v2 + c3_ * v1;
        }
        float R3a = a3 + sA[P3OFF + row1 * 9 + k1] + a1 * sA[8 + jk] + a2 * sA[k1];
        float R3b = c3_ + sA[P3OFF + row2 * 9 + k1] + c1_ * sA[8 + jk] + c2_ * sA[k1];
        float R2v = 0.f, R1v = 0.f;
        if (tid < 64) R2v = sP[8 + tid] + sA[8 + tid] + sP[tid >> 3] * sA[tid & 7];
        if (tid < 8)  R1v = sP[tid] + sA[tid];

        sR[P3OFF + row1 * 9 + k1] = R3a;
        sR[P3OFF + row2 * 9 + k1] = R3b;
        if (tid < 64) sR[8 + tid] = R2v;
        if (tid < 8)  sR[tid] = R1v;
        __syncthreads();

        float q23a = sR[i1] * sR[8 + jk] + sR[8 + row1] * sR[k1];
        float q23b = sR[i2] * sR[8 + jk] + sR[8 + row2] * sR[k1];
        sQ23[row1 * 9 + k1] = q23a;
        sQ23[row2 * 9 + k1] = q23b;
        __syncthreads();

        {
            float s1ia = sR[i1], s1ib = sR[i2], s1j = sR[j1], s1k = sR[k1];
            float s2ija = sR[8 + row1], s2ijb = sR[8 + row2];
            const float* r3p = &sR[P3OFF + jk * 9];
            const float* r2p = &sR[8 + k1 * 8];
            const float* q23p = &sQ23[jk * 9];
#pragma unroll
            for (int l = 0; l < 8; l++) {
                float s1l = sR[l];
                float p22 = s1k * s1l;
                float p24a = s1ia * r3p[l] + s2ija * r2p[l] + R3a * s1l;
                float p24b = s1ib * r3p[l] + s2ijb * r2p[l] + R3b * s1l;
                float p34a = s1ia * q23p[l] + s2ija * p22;
                float p34b = s1ib * q23p[l] + s2ijb * p22;
                float p44a = s1ia * s1j * p22;
                float p44b = s1ib * s1j * p22;
                pool4a[l] += R4a[l] - 0.5f * p24a + (1.f/3.f) * p34a - 0.25f * p44a;
                pool4b[l] += R4b[l] - 0.5f * p24b + (1.f/3.f) * p34b - 0.25f * p44b;
            }
            pool3a += R3a - 0.5f * q23a + (1.f/3.f) * s1ia * s1j * s1k;
            pool3b += R3b - 0.5f * q23b + (1.f/3.f) * s1ib * s1j * s1k;
            if (tid < 64) pool2 += R2v - 0.5f * sR[tid >> 3] * sR[tid & 7];
            if (tid < 8)  pool1 += R1v;
        }
        __syncthreads();
    }

    // plain coalesced partial stores (sum over this block's 4 chunks)
    {
        float* pb = partial + (size_t)blk * MEM;
        float4 va0 = make_float4(pool4a[0], pool4a[1], pool4a[2], pool4a[3]);
        float4 va1 = make_float4(pool4a[4], pool4a[5], pool4a[6], pool4a[7]);
        float4 vb0 = make_float4(pool4b[0], pool4b[1], pool4b[2], pool4b[3]);
        float4 vb1 = make_float4(pool4b[4], pool4b[5], pool4b[6], pool4b[7]);
        float4* d1 = (float4*)(pb + 584 + tid * 8);
        d1[0] = va0; d1[1] = va1;
        float4* d2 = (float4*)(pb + 584 + (tid + 256) * 8);
        d2[0] = vb0; d2[1] = vb1;
        pb[72 + tid] = pool3a;
        pb[72 + tid + 256] = pool3b;
        if (tid < 64) pb[8 + tid] = pool2;
        if (tid < 8)  pb[tid] = pool1;
    }
}

// ------------------------------------------------ kernel 4: reduce partials + gemv -> hpart
__global__ __launch_bounds__(256) void gemv1_kernel(const float* __restrict__ partial,
                                                    const float* __restrict__ W1,
                                                    float* __restrict__ hpart) {
    int kc = blockIdx.x;
    int tid = threadIdx.x;
    int k0 = kc * 32;
    __shared__ float sp[8][32];
    {
        int b = tid >> 5, k = tid & 31;
        float sum = 0.f;
        if (k0 + k < MEM) {
            for (int g = 0; g < NG; g++)
                sum += partial[(size_t)(b * NG + g) * MEM + k0 + k];
        }
        sp[b][k] = sum * (1.f / 128.f);
    }
    __syncthreads();
    float acc[8];
#pragma unroll
    for (int b = 0; b < 8; b++) acc[b] = 0.f;
    int kend = (k0 + 32 < MEM) ? 32 : (MEM - k0);
    for (int k = 0; k < kend; k++) {
        float wv = W1[(size_t)(k0 + k) * 256 + tid];
#pragma unroll
        for (int b = 0; b < 8; b++) acc[b] += sp[b][k] * wv;
    }
#pragma unroll
    for (int b = 0; b < 8; b++) hpart[(size_t)kc * 2048 + b * 256 + tid] = acc[b];
}

// ------------------------------------------------ kernel 5: reduce hpart + final MLP
__global__ __launch_bounds__(256) void final_kernel(const float* __restrict__ hpart,
                                                    const float* __restrict__ b1,
                                                    const float* __restrict__ W2,
                                                    const float* __restrict__ b2,
                                                    float* __restrict__ outp) {
    int b = blockIdx.x;
    int tid = threadIdx.x;
    float v = 0.f;
    for (int kc = 0; kc < 147; kc++) v += hpart[(size_t)kc * 2048 + b * 256 + tid];
    v += b1[tid];
    v = fmaxf(v, 0.f) * W2[tid];
    __shared__ float sRed[256];
    sRed[tid] = v;
    __syncthreads();
    for (int s = 128; s > 0; s >>= 1) {
        if (tid < s) sRed[tid] += sRed[tid + s];
        __syncthreads();
    }
    if (tid == 0) outp[b] = sRed[0] + b2[0];
}

// ------------------------------------------------ launch
extern "C" void kernel_launch(void* const* d_in, const int* in_sizes, int n_in,
                              void* d_out, int out_size, void* d_ws, size_t ws_size,
                              hipStream_t stream) {
    const float* x  = (const float*)d_in[0];
    const float* W1 = (const float*)d_in[1];
    const float* b1 = (const float*)d_in[2];
    const float* W2 = (const float*)d_in[3];
    const float* b2 = (const float*)d_in[4];
    float* out = (float*)d_out;

    float* ws = (float*)d_ws;
    float* T       = ws;                            // 256*MEM (group totals)
    float* P       = T + (size_t)256 * MEM;         // 256*MEM (exclusive prefixes)
    float* partial = P + (size_t)256 * MEM;         // 256*MEM (pooled partials, fully written)
    float* hpart   = partial + (size_t)256 * MEM;   // 147*2048 (gemv partials, fully written)

    sig_totals_kernel<<<256, 256, 0, stream>>>(x, T);
    scan_fused_kernel<<<128, 256, 0, stream>>>(T, P);
    apply_log_pool_kernel<<<256, 256, 0, stream>>>(x, P, partial);
    gemv1_kernel<<<147, 256, 0, stream>>>(partial, W1, hpart);
    final_kernel<<<8, 256, 0, stream>>>(hpart, b1, W2, b2, out);
}